// Round 4
// baseline (753.784 us; speedup 1.0000x reference)
//
#include <hip/hip_runtime.h>

// RWKV chunked wkv recurrence, MI355X (gfx950).  T=32, H=4096, D=64.
// One wave per head, 4 heads per 256-thread block. Lane i owns state row
// S[i][0..63] in VGPRs.
//
// Round-4 structure (R1/R2 were DS-pipe-bound: 32x ds_read_b128 broadcast
// per step ~= 82us of LDS pipe per CU; R3's SMEM-asm variant never ran):
//  - NO LDS, NO barriers, NO inline asm. k_t/r_t are wave-uniform, so they
//    are read directly from global as uniform float4 loads: each lowers to
//    ONE 16B L1/L2 request broadcast to all 64 lanes. Vector loads use
//    counted vmcnt, so the compiler pipelines them under the FMA stream.
//  - v, td are lane-local, streamed with a 2-deep register prefetch.
//  - Unfactored 4-VALU/element update (term-wise identical to reference):
//      kv = v_i*k_j; acc += (tf_i*kv + S_ij)*r_j; S_ij = td_i*S_ij + kv

#define TT 32
#define HH 4096
#define DD 64

__global__ __launch_bounds__(256, 4)
void wkv_chunk_kernel(const float* __restrict__ k,
                      const float* __restrict__ v,
                      const float* __restrict__ r,
                      const float* __restrict__ state_in,
                      const float* __restrict__ td,
                      const float* __restrict__ tf,
                      float* __restrict__ out,        // [T,H,D]
                      float* __restrict__ state_out)  // [H,D,D]
{
    const int lane = threadIdx.x & 63;                                  // row i
    const int wid  = __builtin_amdgcn_readfirstlane(threadIdx.x >> 6);  // wave id
    const int h    = blockIdx.x * 4 + wid;                              // head

    // ---- state row i -> 64 VGPRs ----
    float S[DD];
    {
        const float* sp = state_in + ((size_t)h * DD + lane) * DD;
        #pragma unroll
        for (int jq = 0; jq < DD / 4; ++jq) {
            const float4 s4 = reinterpret_cast<const float4*>(sp)[jq];
            S[4 * jq + 0] = s4.x;
            S[4 * jq + 1] = s4.y;
            S[4 * jq + 2] = s4.z;
            S[4 * jq + 3] = s4.w;
        }
    }
    const float tfi = tf[h * DD + lane];

    const size_t stp = (size_t)HH * DD;
    const float* vp = v  + (size_t)h * DD + lane;
    const float* tp = td + (size_t)h * DD + lane;
    const float* kb = k  + (size_t)h * DD;
    const float* rb = r  + (size_t)h * DD;

    float v0 = vp[0], v1 = vp[stp];
    float d0 = tp[0], d1 = tp[stp];

    for (int t = 0; t < TT; ++t) {
        const int tpre = (t + 2 < TT) ? (t + 2) : (TT - 1);  // clamped prefetch
        const float v2 = vp[(size_t)tpre * stp];
        const float d2 = tp[(size_t)tpre * stp];

        // wave-uniform addresses: one 16B broadcast request per float4 load
        const float4* kt4 = reinterpret_cast<const float4*>(kb + (size_t)t * stp);
        const float4* rt4 = reinterpret_cast<const float4*>(rb + (size_t)t * stp);

        const float vi = v0, tdi = d0;
        float a0 = 0.f, a1 = 0.f, a2 = 0.f, a3 = 0.f;

        #pragma unroll
        for (int jq = 0; jq < DD / 4; ++jq) {
            const float4 k4 = kt4[jq];
            const float4 r4 = rt4[jq];
            float kv;
            kv = vi * k4.x;
            a0 = fmaf(fmaf(tfi, kv, S[4 * jq + 0]), r4.x, a0);
            S[4 * jq + 0] = fmaf(tdi, S[4 * jq + 0], kv);
            kv = vi * k4.y;
            a1 = fmaf(fmaf(tfi, kv, S[4 * jq + 1]), r4.y, a1);
            S[4 * jq + 1] = fmaf(tdi, S[4 * jq + 1], kv);
            kv = vi * k4.z;
            a2 = fmaf(fmaf(tfi, kv, S[4 * jq + 2]), r4.z, a2);
            S[4 * jq + 2] = fmaf(tdi, S[4 * jq + 2], kv);
            kv = vi * k4.w;
            a3 = fmaf(fmaf(tfi, kv, S[4 * jq + 3]), r4.w, a3);
            S[4 * jq + 3] = fmaf(tdi, S[4 * jq + 3], kv);
        }

        out[((size_t)t * HH + h) * DD + lane] = (a0 + a1) + (a2 + a3);

        v0 = v1; v1 = v2;
        d0 = d1; d1 = d2;
    }

    // ---- final state row ----
    {
        float* sp = state_out + ((size_t)h * DD + lane) * DD;
        #pragma unroll
        for (int jq = 0; jq < DD / 4; ++jq) {
            float4 s4;
            s4.x = S[4 * jq + 0];
            s4.y = S[4 * jq + 1];
            s4.z = S[4 * jq + 2];
            s4.w = S[4 * jq + 3];
            reinterpret_cast<float4*>(sp)[jq] = s4;
        }
    }
}

extern "C" void kernel_launch(void* const* d_in, const int* in_sizes, int n_in,
                              void* d_out, int out_size, void* d_ws, size_t ws_size,
                              hipStream_t stream) {
    const float* k     = (const float*)d_in[0];  // [T,H,1,D]
    const float* v     = (const float*)d_in[1];  // [T,H,D,1]
    const float* r     = (const float*)d_in[2];  // [T,H,D,1]
    const float* state = (const float*)d_in[3];  // [H,D,D]
    const float* td    = (const float*)d_in[4];  // [T,H,D,1]
    const float* tf    = (const float*)d_in[5];  // [H,D,1]

    float* out       = (float*)d_out;                         // [T,H,D]
    float* state_out = (float*)d_out + (size_t)TT * HH * DD;  // [H,D,D]

    wkv_chunk_kernel<<<dim3(HH / 4), dim3(256), 0, stream>>>(
        k, v, r, state, td, tf, out, state_out);
}